// Round 1
// baseline (342.243 us; speedup 1.0000x reference)
//
#include <hip/hip_runtime.h>

typedef __attribute__((ext_vector_type(4))) float f32x4;
typedef __attribute__((ext_vector_type(8))) __bf16 bf16x8;
typedef __attribute__((ext_vector_type(8))) unsigned short u16x8;
typedef __attribute__((ext_vector_type(4))) unsigned short u16x4;

// f32 -> bf16 round-to-nearest-even (bit pattern)
__device__ __forceinline__ unsigned short f2bf(float f) {
  unsigned u = __builtin_bit_cast(unsigned, f);
  u += 0x7fffu + ((u >> 16) & 1u);
  return (unsigned short)(u >> 16);
}

__device__ __forceinline__ f32x4 mfma16(bf16x8 a, bf16x8 b, f32x4 c) {
  return __builtin_amdgcn_mfma_f32_16x16x32_bf16(a, b, c, 0, 0, 0);
}

__device__ __forceinline__ void gload_lds16(const void* g, void* l) {
  __builtin_amdgcn_global_load_lds(
      (const __attribute__((address_space(1))) void*)g,
      (__attribute__((address_space(3))) void*)l, 16, 0, 0);
}

// ---------------------------------------------------------------------------
// Kernel 1: W [768K x 768N] f32  ->  Wt [768N x 768K] bf16   (x3 for q,k,v)
// ---------------------------------------------------------------------------
__global__ __launch_bounds__(256) void wtrans_kernel(
    const float* __restrict__ Wq, const float* __restrict__ Wk,
    const float* __restrict__ Wv, unsigned short* __restrict__ Wt) {
  __shared__ float tile[64][65];
  const int z = blockIdx.z;
  const float* __restrict__ src = (z == 0) ? Wq : (z == 1) ? Wk : Wv;
  unsigned short* __restrict__ dst = Wt + (size_t)z * 768 * 768;
  const int k0 = blockIdx.x * 64, n0 = blockIdx.y * 64;
  const int t = threadIdx.x;
  const int r = t >> 4, c4 = (t & 15) * 4;
#pragma unroll
  for (int p = 0; p < 4; ++p) {
    int rr = r + p * 16;
    f32x4 v = *(const f32x4*)(src + (size_t)(k0 + rr) * 768 + n0 + c4);
#pragma unroll
    for (int j = 0; j < 4; ++j) tile[rr][c4 + j] = v[j];
  }
  __syncthreads();
#pragma unroll
  for (int p = 0; p < 4; ++p) {
    int rn = r + p * 16;
    u16x4 o;
#pragma unroll
    for (int j = 0; j < 4; ++j) o[j] = f2bf(tile[c4 + j][rn]);
    *(u16x4*)(dst + (size_t)(n0 + rn) * 768 + k0 + c4) = o;
  }
}

// ---------------------------------------------------------------------------
// Kernel 2: QKV projection. C = X[8192x768] * W[768x768] + b  (bf16 MFMA)
// out: qkv [3][B=2][H=12][S=4096][D=64] bf16; q pre-scaled by 0.125
// ---------------------------------------------------------------------------
__global__ __launch_bounds__(256) void qkv_gemm_kernel(
    const float* __restrict__ from_t, const float* __restrict__ to_t,
    const unsigned short* __restrict__ Wt,
    const float* __restrict__ bq, const float* __restrict__ bk,
    const float* __restrict__ bv, unsigned short* __restrict__ qkv) {
  __shared__ unsigned short A_lds[128][40];  // +8 pad -> conflict-free frag reads
  __shared__ unsigned short B_lds[4096];     // [128n][32k] linear, src-swizzled
  const int z = blockIdx.z;
  const float* __restrict__ X = (z == 0) ? from_t : to_t;
  const unsigned short* __restrict__ Wz = Wt + (size_t)z * 768 * 768;
  const float* __restrict__ bias = (z == 0) ? bq : (z == 1) ? bk : bv;
  const int bm = blockIdx.x, bn = blockIdx.y;
  const int t = threadIdx.x, lane = t & 63, w = t >> 6;
  const int wm = (w >> 1) * 64, wn = (w & 1) * 64;

  f32x4 acc[4][4];
#pragma unroll
  for (int i = 0; i < 4; ++i)
#pragma unroll
    for (int j = 0; j < 4; ++j) acc[i][j] = (f32x4){0.f, 0.f, 0.f, 0.f};

  for (int ks = 0; ks < 24; ++ks) {
    // stage A: f32 load -> bf16 convert -> LDS (padded rows)
#pragma unroll
    for (int p = 0; p < 4; ++p) {
      int idx = p * 256 + t;
      int r = idx >> 3, c4i = idx & 7;
      f32x4 v = *(const f32x4*)(X + (size_t)(bm * 128 + r) * 768 + ks * 32 + c4i * 4);
      u16x4 o;
#pragma unroll
      for (int j = 0; j < 4; ++j) o[j] = f2bf(v[j]);
      *(u16x4*)(&A_lds[r][c4i * 4]) = o;
    }
    // stage B: global_load_lds, source 16B-chunk permuted by (row&3)
#pragma unroll
    for (int p = 0; p < 2; ++p) {
      int chunk = p * 4 + w;          // wave-uniform
      int idx = chunk * 64 + lane;
      int r = idx >> 2, c = idx & 3;
      const unsigned short* src =
          Wz + (size_t)(bn * 128 + r) * 768 + ks * 32 + ((c ^ (r & 3)) * 8);
      gload_lds16(src, &B_lds[chunk * 512]);
    }
    __syncthreads();

    bf16x8 af[4], bfr[4];
#pragma unroll
    for (int mi = 0; mi < 4; ++mi) {
      int row = wm + mi * 16 + (lane & 15);
      af[mi] = *(const bf16x8*)(&A_lds[row][(lane >> 4) * 8]);
    }
#pragma unroll
    for (int ni = 0; ni < 4; ++ni) {
      int rw = wn + ni * 16 + (lane & 15);
      int cc = lane >> 4;
      bfr[ni] = *(const bf16x8*)((const char*)B_lds + rw * 64 + ((cc ^ (rw & 3)) << 4));
    }
#pragma unroll
    for (int mi = 0; mi < 4; ++mi)
#pragma unroll
      for (int ni = 0; ni < 4; ++ni)
        acc[mi][ni] = mfma16(af[mi], bfr[ni], acc[mi][ni]);
    __syncthreads();
  }

  const float qscale = (z == 0) ? 0.125f : 1.0f;  // fold attention scale into Q
#pragma unroll
  for (int ni = 0; ni < 4; ++ni) {
    int gn = bn * 128 + wn + ni * 16 + (lane & 15);
    float bv_ = bias[gn];
    int hh = gn >> 6, dd = gn & 63;
#pragma unroll
    for (int mi = 0; mi < 4; ++mi) {
#pragma unroll
      for (int r = 0; r < 4; ++r) {
        int gm = bm * 128 + wm + mi * 16 + (lane >> 4) * 4 + r;
        int bb = gm >> 12, s = gm & 4095;
        float val = (acc[mi][ni][r] + bv_) * qscale;
        qkv[((((size_t)z * 2 + bb) * 12 + hh) * 4096 + s) * 64 + dd] = f2bf(val);
      }
    }
  }
}

// ---------------------------------------------------------------------------
// Kernel 3: block-sparse attention, one workgroup per (b,h,m), 4 waves.
// Flash-style online softmax over the key-block list.
// ---------------------------------------------------------------------------
__global__ __launch_bounds__(256) void attn_kernel(
    const unsigned short* __restrict__ qkv, const int* __restrict__ to_mask,
    const int* __restrict__ rand_attn, float* __restrict__ out) {
  __shared__ unsigned short K_lds[4096];    // [64key][64d], src-chunk swizzled
  __shared__ unsigned short VT_lds[4096];   // [64d][64key], swizzled
  __shared__ unsigned short P_lds[4][1024]; // per-wave [16q][64k], swizzled
  __shared__ float penal[64];
  __shared__ int blist[64];

  const int bid = blockIdx.x;
  const int m = bid & 63;
  const int hb = bid >> 6;
  const int h = hb % 12;
  const int b = hb / 12;
  const int t = threadIdx.x, lane = t & 63, w = t >> 6;

  int nblk;
  if (m == 0 || m == 63) {
    nblk = 64;
    if (t < 64) blist[t] = t;
  } else {
    nblk = (m == 1 || m == 62) ? 7 : 8;
    if (t == 0) {
      const int* rp = rand_attn + ((size_t)h * 62 + (m - 1)) * 3;
      if (m == 1) {
        blist[0] = 0; blist[1] = 1; blist[2] = 2; blist[3] = 63;
        blist[4] = rp[0]; blist[5] = rp[1]; blist[6] = rp[2];
      } else if (m == 62) {
        blist[0] = 0; blist[1] = 61; blist[2] = 62; blist[3] = 63;
        blist[4] = rp[0]; blist[5] = rp[1]; blist[6] = rp[2];
      } else {
        blist[0] = m - 1; blist[1] = m; blist[2] = m + 1;
        blist[3] = rp[0]; blist[4] = rp[1]; blist[5] = rp[2];
        blist[6] = 0; blist[7] = 63;
      }
    }
  }

  const unsigned short* qp = qkv + (((size_t)b * 12 + h) * 4096 + m * 64) * 64;
  const unsigned short* kp = qkv + (((size_t)(2 + b) * 12 + h) * 4096) * 64;
  const unsigned short* vp = qkv + (((size_t)(4 + b) * 12 + h) * 4096) * 64;

  bf16x8 aq[2];
  {
    int qrow = w * 16 + (lane & 15);
    aq[0] = *(const bf16x8*)(qp + qrow * 64 + (lane >> 4) * 8);
    aq[1] = *(const bf16x8*)(qp + qrow * 64 + 32 + (lane >> 4) * 8);
  }

  float m_run[4], l_run[4];
  f32x4 o_acc[4];
#pragma unroll
  for (int r = 0; r < 4; ++r) { m_run[r] = -INFINITY; l_run[r] = 0.f; }
#pragma unroll
  for (int dg = 0; dg < 4; ++dg) o_acc[dg] = (f32x4){0.f, 0.f, 0.f, 0.f};

  __syncthreads();  // blist visible

  for (int ib = 0; ib < nblk; ++ib) {
    const int kb = blist[ib];
    // stage K via global_load_lds (source chunk permuted by row&7)
#pragma unroll
    for (int p = 0; p < 2; ++p) {
      int chunk = p * 4 + w;  // wave-uniform
      int idx = chunk * 64 + lane;
      int r = idx >> 3, c = idx & 7;
      const unsigned short* src =
          kp + (size_t)(kb * 64 + r) * 64 + ((c ^ (r & 7)) * 8);
      gload_lds16(src, &K_lds[chunk * 512]);
    }
    // stage V transposed (reg path), both-axis swizzle
#pragma unroll
    for (int p = 0; p < 2; ++p) {
      int idx = p * 256 + t;
      int r = idx >> 3, c = idx & 7;
      u16x8 vv = *(const u16x8*)(vp + (size_t)(kb * 64 + r) * 64 + c * 8);
#pragma unroll
      for (int j = 0; j < 8; ++j) {
        int d = c * 8 + j;
        int sd = ((d >> 3) ^ d) & 7;
        int byteoff = d * 128 + (((r >> 3) ^ sd) << 4) + (r & 7) * 2;
        *(unsigned short*)((char*)VT_lds + byteoff) = vv[j];
      }
    }
    if (t < 64)
      penal[t] = (1.0f - (float)to_mask[(size_t)b * 4096 + kb * 64 + t]) * (-1e9f);
    __syncthreads();

    // QK^T (scale already folded into Q)
    f32x4 sf[4];
#pragma unroll
    for (int kg = 0; kg < 4; ++kg) {
      int krow = kg * 16 + (lane & 15);
      int cc = lane >> 4;
      const char* kb_ = (const char*)K_lds + krow * 128;
      bf16x8 b0 = *(const bf16x8*)(kb_ + ((cc ^ (krow & 7)) << 4));
      bf16x8 b1 = *(const bf16x8*)(kb_ + (((cc + 4) ^ (krow & 7)) << 4));
      f32x4 zz = (f32x4){0.f, 0.f, 0.f, 0.f};
      zz = mfma16(aq[0], b0, zz);
      zz = mfma16(aq[1], b1, zz);
      sf[kg] = zz;
    }

    float sm[4][4];
#pragma unroll
    for (int kg = 0; kg < 4; ++kg) {
      float pen = penal[kg * 16 + (lane & 15)];
#pragma unroll
      for (int r = 0; r < 4; ++r) sm[kg][r] = sf[kg][r] + pen;
    }
    float mx[4];
#pragma unroll
    for (int r = 0; r < 4; ++r)
      mx[r] = fmaxf(fmaxf(sm[0][r], sm[1][r]), fmaxf(sm[2][r], sm[3][r]));
#pragma unroll
    for (int msk = 1; msk < 16; msk <<= 1)
#pragma unroll
      for (int r = 0; r < 4; ++r)
        mx[r] = fmaxf(mx[r], __shfl_xor(mx[r], msk, 64));

    float fac[4], rs[4];
#pragma unroll
    for (int r = 0; r < 4; ++r) {
      float mn = fmaxf(m_run[r], mx[r]);
      fac[r] = __expf(m_run[r] - mn);
      m_run[r] = mn;
      rs[r] = 0.f;
    }
    unsigned short pb[4][4];
#pragma unroll
    for (int kg = 0; kg < 4; ++kg)
#pragma unroll
      for (int r = 0; r < 4; ++r) {
        float p = __expf(sm[kg][r] - m_run[r]);
        rs[r] += p;
        pb[kg][r] = f2bf(p);
      }
#pragma unroll
    for (int msk = 1; msk < 16; msk <<= 1)
#pragma unroll
      for (int r = 0; r < 4; ++r) rs[r] += __shfl_xor(rs[r], msk, 64);
#pragma unroll
    for (int r = 0; r < 4; ++r) l_run[r] = l_run[r] * fac[r] + rs[r];
#pragma unroll
    for (int dg = 0; dg < 4; ++dg)
#pragma unroll
      for (int r = 0; r < 4; ++r) o_acc[dg][r] *= fac[r];

    // P (C-layout) -> LDS transpose -> A-frags, per-wave region
    char* pw = (char*)P_lds[w];
#pragma unroll
    for (int kg = 0; kg < 4; ++kg)
#pragma unroll
      for (int r = 0; r < 4; ++r) {
        int q = (lane >> 4) * 4 + r;
        int k = kg * 16 + (lane & 15);
        int byteoff = q * 128 + (((k >> 3) ^ (q & 7)) << 4) + (k & 7) * 2;
        *(unsigned short*)(pw + byteoff) = pb[kg][r];
      }
    bf16x8 ap[2];
    {
      int q = lane & 15;
      int cc = lane >> 4;
      ap[0] = *(const bf16x8*)(pw + q * 128 + ((cc ^ (q & 7)) << 4));
      ap[1] = *(const bf16x8*)(pw + q * 128 + (((cc + 4) ^ (q & 7)) << 4));
    }
    // PV
#pragma unroll
    for (int dg = 0; dg < 4; ++dg) {
      int d = dg * 16 + (lane & 15);
      int sd = ((d >> 3) ^ d) & 7;
      int cc = lane >> 4;
      const char* vb = (const char*)VT_lds + d * 128;
      bf16x8 b0 = *(const bf16x8*)(vb + ((cc ^ sd) << 4));
      bf16x8 b1 = *(const bf16x8*)(vb + (((cc + 4) ^ sd) << 4));
      o_acc[dg] = mfma16(ap[0], b0, o_acc[dg]);
      o_acc[dg] = mfma16(ap[1], b1, o_acc[dg]);
    }
    __syncthreads();
  }

  // epilogue: normalize and store [B,S,H,D] f32
#pragma unroll
  for (int r = 0; r < 4; ++r) {
    float inv = 1.0f / l_run[r];
    int s = m * 64 + w * 16 + (lane >> 4) * 4 + r;
#pragma unroll
    for (int dg = 0; dg < 4; ++dg) {
      int d = dg * 16 + (lane & 15);
      out[(((size_t)b * 4096 + s) * 12 + h) * 64 + d] = o_acc[dg][r] * inv;
    }
  }
}

// ---------------------------------------------------------------------------
extern "C" void kernel_launch(void* const* d_in, const int* in_sizes, int n_in,
                              void* d_out, int out_size, void* d_ws,
                              size_t ws_size, hipStream_t stream) {
  (void)in_sizes; (void)n_in; (void)out_size; (void)ws_size;
  const float* from_t = (const float*)d_in[0];
  const float* to_t = (const float*)d_in[1];
  const float* Wq = (const float*)d_in[2];
  const float* bq = (const float*)d_in[3];
  const float* Wk = (const float*)d_in[4];
  const float* bk = (const float*)d_in[5];
  const float* Wv = (const float*)d_in[6];
  const float* bv = (const float*)d_in[7];
  const int* to_mask = (const int*)d_in[8];
  const int* rand_attn = (const int*)d_in[9];
  float* out = (float*)d_out;

  unsigned short* Wt = (unsigned short*)d_ws;           // 3*768*768 bf16
  unsigned short* qkv = Wt + (size_t)3 * 768 * 768;     // 3*2*12*4096*64 bf16

  wtrans_kernel<<<dim3(12, 12, 3), dim3(256), 0, stream>>>(Wq, Wk, Wv, Wt);
  qkv_gemm_kernel<<<dim3(64, 6, 3), dim3(256), 0, stream>>>(
      from_t, to_t, Wt, bq, bk, bv, qkv);
  attn_kernel<<<dim3(2 * 12 * 64), dim3(256), 0, stream>>>(
      qkv, to_mask, rand_attn, out);
}

// Round 2
// 139.798 us; speedup vs baseline: 2.4481x; 2.4481x over previous
//
#include <hip/hip_runtime.h>

typedef __attribute__((ext_vector_type(4))) float f32x4;
typedef __attribute__((ext_vector_type(8))) __bf16 bf16x8;
typedef __attribute__((ext_vector_type(8))) unsigned short u16x8;
typedef __attribute__((ext_vector_type(4))) unsigned short u16x4;

// f32 -> bf16 round-to-nearest-even (bit pattern)
__device__ __forceinline__ unsigned short f2bf(float f) {
  unsigned u = __builtin_bit_cast(unsigned, f);
  u += 0x7fffu + ((u >> 16) & 1u);
  return (unsigned short)(u >> 16);
}

__device__ __forceinline__ f32x4 mfma16(bf16x8 a, bf16x8 b, f32x4 c) {
  return __builtin_amdgcn_mfma_f32_16x16x32_bf16(a, b, c, 0, 0, 0);
}

__device__ __forceinline__ void gload_lds16(const void* g, void* l) {
  __builtin_amdgcn_global_load_lds(
      (const __attribute__((address_space(1))) void*)g,
      (__attribute__((address_space(3))) void*)l, 16, 0, 0);
}

// ---------------------------------------------------------------------------
// Kernel 1: W [768K x 768N] f32  ->  Wt [768N x 768K] bf16   (x3 for q,k,v)
// ---------------------------------------------------------------------------
__global__ __launch_bounds__(256) void wtrans_kernel(
    const float* __restrict__ Wq, const float* __restrict__ Wk,
    const float* __restrict__ Wv, unsigned short* __restrict__ Wt) {
  __shared__ float tile[64][65];
  const int z = blockIdx.z;
  const float* __restrict__ src = (z == 0) ? Wq : (z == 1) ? Wk : Wv;
  unsigned short* __restrict__ dst = Wt + (size_t)z * 768 * 768;
  const int k0 = blockIdx.x * 64, n0 = blockIdx.y * 64;
  const int t = threadIdx.x;
  const int r = t >> 4, c4 = (t & 15) * 4;
#pragma unroll
  for (int p = 0; p < 4; ++p) {
    int rr = r + p * 16;
    f32x4 v = *(const f32x4*)(src + (size_t)(k0 + rr) * 768 + n0 + c4);
#pragma unroll
    for (int j = 0; j < 4; ++j) tile[rr][c4 + j] = v[j];
  }
  __syncthreads();
#pragma unroll
  for (int p = 0; p < 4; ++p) {
    int rn = r + p * 16;
    u16x4 o;
#pragma unroll
    for (int j = 0; j < 4; ++j) o[j] = f2bf(tile[c4 + j][rn]);
    *(u16x4*)(dst + (size_t)(n0 + rn) * 768 + k0 + c4) = o;
  }
}

// ---------------------------------------------------------------------------
// Kernel 2: QKV projection. C = X[8192x768] * W[768x768] + b  (bf16 MFMA)
// out: qkv [3][B=2][H=12][S=4096][D=64] bf16; q pre-scaled by 0.125
// ---------------------------------------------------------------------------
__global__ __launch_bounds__(256) void qkv_gemm_kernel(
    const float* __restrict__ from_t, const float* __restrict__ to_t,
    const unsigned short* __restrict__ Wt,
    const float* __restrict__ bq, const float* __restrict__ bk,
    const float* __restrict__ bv, unsigned short* __restrict__ qkv) {
  __shared__ unsigned short A_lds[128][40];  // +8 pad -> conflict-free frag reads
  __shared__ unsigned short B_lds[4096];     // [128n][32k] linear, src-swizzled
  const int z = blockIdx.z;
  const float* __restrict__ X = (z == 0) ? from_t : to_t;
  const unsigned short* __restrict__ Wz = Wt + (size_t)z * 768 * 768;
  const float* __restrict__ bias = (z == 0) ? bq : (z == 1) ? bk : bv;
  const int bm = blockIdx.x, bn = blockIdx.y;
  const int t = threadIdx.x, lane = t & 63, w = t >> 6;
  const int wm = (w >> 1) * 64, wn = (w & 1) * 64;

  f32x4 acc[4][4];
#pragma unroll
  for (int i = 0; i < 4; ++i)
#pragma unroll
    for (int j = 0; j < 4; ++j) acc[i][j] = (f32x4){0.f, 0.f, 0.f, 0.f};

  for (int ks = 0; ks < 24; ++ks) {
    // stage A: f32 load -> bf16 convert -> LDS (padded rows)
#pragma unroll
    for (int p = 0; p < 4; ++p) {
      int idx = p * 256 + t;
      int r = idx >> 3, c4i = idx & 7;
      f32x4 v = *(const f32x4*)(X + (size_t)(bm * 128 + r) * 768 + ks * 32 + c4i * 4);
      u16x4 o;
#pragma unroll
      for (int j = 0; j < 4; ++j) o[j] = f2bf(v[j]);
      *(u16x4*)(&A_lds[r][c4i * 4]) = o;
    }
    // stage B: global_load_lds, source 16B-chunk permuted by (row&3)
#pragma unroll
    for (int p = 0; p < 2; ++p) {
      int chunk = p * 4 + w;          // wave-uniform
      int idx = chunk * 64 + lane;
      int r = idx >> 2, c = idx & 3;
      const unsigned short* src =
          Wz + (size_t)(bn * 128 + r) * 768 + ks * 32 + ((c ^ (r & 3)) * 8);
      gload_lds16(src, &B_lds[chunk * 512]);
    }
    __syncthreads();

    bf16x8 af[4], bfr[4];
#pragma unroll
    for (int mi = 0; mi < 4; ++mi) {
      int row = wm + mi * 16 + (lane & 15);
      af[mi] = *(const bf16x8*)(&A_lds[row][(lane >> 4) * 8]);
    }
#pragma unroll
    for (int ni = 0; ni < 4; ++ni) {
      int rw = wn + ni * 16 + (lane & 15);
      int cc = lane >> 4;
      bfr[ni] = *(const bf16x8*)((const char*)B_lds + rw * 64 + ((cc ^ (rw & 3)) << 4));
    }
#pragma unroll
    for (int mi = 0; mi < 4; ++mi)
#pragma unroll
      for (int ni = 0; ni < 4; ++ni)
        acc[mi][ni] = mfma16(af[mi], bfr[ni], acc[mi][ni]);
    __syncthreads();
  }

  const float qscale = (z == 0) ? 0.125f : 1.0f;  // fold attention scale into Q
#pragma unroll
  for (int ni = 0; ni < 4; ++ni) {
    int gn = bn * 128 + wn + ni * 16 + (lane & 15);
    float bv_ = bias[gn];
    int hh = gn >> 6, dd = gn & 63;
#pragma unroll
    for (int mi = 0; mi < 4; ++mi) {
#pragma unroll
      for (int r = 0; r < 4; ++r) {
        int gm = bm * 128 + wm + mi * 16 + (lane >> 4) * 4 + r;
        int bb = gm >> 12, s = gm & 4095;
        float val = (acc[mi][ni][r] + bv_) * qscale;
        qkv[((((size_t)z * 2 + bb) * 12 + hh) * 4096 + s) * 64 + dd] = f2bf(val);
      }
    }
  }
}

// ---------------------------------------------------------------------------
// Kernel 3: block-sparse attention.
//   blocks [0,1488): sparse rows m=1..62, one wg per (b,h,m), <=8 key blocks,
//                    normalized output straight to `out`.
//   blocks [1488,1872): full rows m in {0,63} split-K: 8 chunks x 8 key
//                    blocks; unnormalized partial (o, m, l) to workspace.
// ---------------------------------------------------------------------------
__global__ __launch_bounds__(256) void attn_kernel(
    const unsigned short* __restrict__ qkv, const int* __restrict__ to_mask,
    const int* __restrict__ rand_attn, float* __restrict__ out,
    float* __restrict__ part_o, float* __restrict__ part_ml) {
  __shared__ unsigned short K_lds[4096];    // [64key][64d], src-chunk swizzled
  __shared__ unsigned short VT_lds[4096];   // [64d][64key], swizzled
  __shared__ unsigned short P_lds[4][1024]; // per-wave [16q][64k], swizzled
  __shared__ float penal[64];
  __shared__ int blist[8];

  const int bid = blockIdx.x;
  const int t = threadIdx.x, lane = t & 63, w = t >> 6;

  int b, h, m, nblk, chunk = 0;
  bool full;
  if (bid < 1488) {
    full = false;
    m = bid % 62 + 1;
    int hb = bid / 62;
    h = hb % 12;
    b = hb / 12;
    nblk = (m == 1 || m == 62) ? 7 : 8;
    if (t == 0) {
      const int* rp = rand_attn + ((size_t)h * 62 + (m - 1)) * 3;
      if (m == 1) {
        blist[0] = 0; blist[1] = 1; blist[2] = 2; blist[3] = 63;
        blist[4] = rp[0]; blist[5] = rp[1]; blist[6] = rp[2];
      } else if (m == 62) {
        blist[0] = 0; blist[1] = 61; blist[2] = 62; blist[3] = 63;
        blist[4] = rp[0]; blist[5] = rp[1]; blist[6] = rp[2];
      } else {
        blist[0] = m - 1; blist[1] = m; blist[2] = m + 1;
        blist[3] = rp[0]; blist[4] = rp[1]; blist[5] = rp[2];
        blist[6] = 0; blist[7] = 63;
      }
    }
  } else {
    full = true;
    int cid = bid - 1488;
    chunk = cid & 7;
    int rest = cid >> 3;
    m = (rest & 1) ? 63 : 0;
    h = (rest >> 1) % 12;
    b = rest / 24;
    nblk = 8;
  }

  const unsigned short* qp = qkv + (((size_t)b * 12 + h) * 4096 + m * 64) * 64;
  const unsigned short* kp = qkv + (((size_t)(2 + b) * 12 + h) * 4096) * 64;
  const unsigned short* vp = qkv + (((size_t)(4 + b) * 12 + h) * 4096) * 64;

  bf16x8 aq[2];
  {
    int qrow = w * 16 + (lane & 15);
    aq[0] = *(const bf16x8*)(qp + qrow * 64 + (lane >> 4) * 8);
    aq[1] = *(const bf16x8*)(qp + qrow * 64 + 32 + (lane >> 4) * 8);
  }

  float m_run[4], l_run[4];
  f32x4 o_acc[4];
#pragma unroll
  for (int r = 0; r < 4; ++r) { m_run[r] = -INFINITY; l_run[r] = 0.f; }
#pragma unroll
  for (int dg = 0; dg < 4; ++dg) o_acc[dg] = (f32x4){0.f, 0.f, 0.f, 0.f};

  __syncthreads();  // blist visible

  for (int ib = 0; ib < nblk; ++ib) {
    const int kb = full ? (chunk * 8 + ib) : blist[ib];
    // stage K via global_load_lds (source chunk permuted by row&7)
#pragma unroll
    for (int p = 0; p < 2; ++p) {
      int chnk = p * 4 + w;  // wave-uniform
      int idx = chnk * 64 + lane;
      int r = idx >> 3, c = idx & 7;
      const unsigned short* src =
          kp + (size_t)(kb * 64 + r) * 64 + ((c ^ (r & 7)) * 8);
      gload_lds16(src, &K_lds[chnk * 512]);
    }
    // stage V transposed (reg path), both-axis swizzle
#pragma unroll
    for (int p = 0; p < 2; ++p) {
      int idx = p * 256 + t;
      int r = idx >> 3, c = idx & 7;
      u16x8 vv = *(const u16x8*)(vp + (size_t)(kb * 64 + r) * 64 + c * 8);
#pragma unroll
      for (int j = 0; j < 8; ++j) {
        int d = c * 8 + j;
        int sd = ((d >> 3) ^ d) & 7;
        int byteoff = d * 128 + (((r >> 3) ^ sd) << 4) + (r & 7) * 2;
        *(unsigned short*)((char*)VT_lds + byteoff) = vv[j];
      }
    }
    if (t < 64)
      penal[t] = (1.0f - (float)to_mask[(size_t)b * 4096 + kb * 64 + t]) * (-1e9f);
    __syncthreads();

    // QK^T (scale already folded into Q)
    f32x4 sf[4];
#pragma unroll
    for (int kg = 0; kg < 4; ++kg) {
      int krow = kg * 16 + (lane & 15);
      int cc = lane >> 4;
      const char* kb_ = (const char*)K_lds + krow * 128;
      bf16x8 b0 = *(const bf16x8*)(kb_ + ((cc ^ (krow & 7)) << 4));
      bf16x8 b1 = *(const bf16x8*)(kb_ + (((cc + 4) ^ (krow & 7)) << 4));
      f32x4 zz = (f32x4){0.f, 0.f, 0.f, 0.f};
      zz = mfma16(aq[0], b0, zz);
      zz = mfma16(aq[1], b1, zz);
      sf[kg] = zz;
    }

    float sm[4][4];
#pragma unroll
    for (int kg = 0; kg < 4; ++kg) {
      float pen = penal[kg * 16 + (lane & 15)];
#pragma unroll
      for (int r = 0; r < 4; ++r) sm[kg][r] = sf[kg][r] + pen;
    }
    float mx[4];
#pragma unroll
    for (int r = 0; r < 4; ++r)
      mx[r] = fmaxf(fmaxf(sm[0][r], sm[1][r]), fmaxf(sm[2][r], sm[3][r]));
#pragma unroll
    for (int msk = 1; msk < 16; msk <<= 1)
#pragma unroll
      for (int r = 0; r < 4; ++r)
        mx[r] = fmaxf(mx[r], __shfl_xor(mx[r], msk, 64));

    float fac[4], rs[4];
#pragma unroll
    for (int r = 0; r < 4; ++r) {
      float mn = fmaxf(m_run[r], mx[r]);
      fac[r] = __expf(m_run[r] - mn);
      m_run[r] = mn;
      rs[r] = 0.f;
    }
    unsigned short pb[4][4];
#pragma unroll
    for (int kg = 0; kg < 4; ++kg)
#pragma unroll
      for (int r = 0; r < 4; ++r) {
        float p = __expf(sm[kg][r] - m_run[r]);
        rs[r] += p;
        pb[kg][r] = f2bf(p);
      }
#pragma unroll
    for (int msk = 1; msk < 16; msk <<= 1)
#pragma unroll
      for (int r = 0; r < 4; ++r) rs[r] += __shfl_xor(rs[r], msk, 64);
#pragma unroll
    for (int r = 0; r < 4; ++r) l_run[r] = l_run[r] * fac[r] + rs[r];
#pragma unroll
    for (int dg = 0; dg < 4; ++dg)
#pragma unroll
      for (int r = 0; r < 4; ++r) o_acc[dg][r] *= fac[r];

    // P (C-layout) -> LDS transpose -> A-frags, per-wave region
    char* pw = (char*)P_lds[w];
#pragma unroll
    for (int kg = 0; kg < 4; ++kg)
#pragma unroll
      for (int r = 0; r < 4; ++r) {
        int q = (lane >> 4) * 4 + r;
        int k = kg * 16 + (lane & 15);
        int byteoff = q * 128 + (((k >> 3) ^ (q & 7)) << 4) + (k & 7) * 2;
        *(unsigned short*)(pw + byteoff) = pb[kg][r];
      }
    bf16x8 ap[2];
    {
      int q = lane & 15;
      int cc = lane >> 4;
      ap[0] = *(const bf16x8*)(pw + q * 128 + ((cc ^ (q & 7)) << 4));
      ap[1] = *(const bf16x8*)(pw + q * 128 + (((cc + 4) ^ (q & 7)) << 4));
    }
    // PV
#pragma unroll
    for (int dg = 0; dg < 4; ++dg) {
      int d = dg * 16 + (lane & 15);
      int sd = ((d >> 3) ^ d) & 7;
      int cc = lane >> 4;
      const char* vb = (const char*)VT_lds + d * 128;
      bf16x8 b0 = *(const bf16x8*)(vb + ((cc ^ sd) << 4));
      bf16x8 b1 = *(const bf16x8*)(vb + (((cc + 4) ^ sd) << 4));
      o_acc[dg] = mfma16(ap[0], b0, o_acc[dg]);
      o_acc[dg] = mfma16(ap[1], b1, o_acc[dg]);
    }
    __syncthreads();
  }

  if (!full) {
    // normalize and store [B,S,H,D] f32
#pragma unroll
    for (int r = 0; r < 4; ++r) {
      float inv = 1.0f / l_run[r];
      int s = m * 64 + w * 16 + (lane >> 4) * 4 + r;
#pragma unroll
      for (int dg = 0; dg < 4; ++dg) {
        int d = dg * 16 + (lane & 15);
        out[(((size_t)b * 4096 + s) * 12 + h) * 64 + d] = o_acc[dg][r] * inv;
      }
    }
  } else {
    // store unnormalized partials: part_o[row][chunk][64q][64d], ml[row][chunk][2][64]
    const int row = (b * 12 + h) * 2 + (m ? 1 : 0);
    float* po = part_o + (((size_t)row * 8 + chunk) * 64) * 64;
    float* pml = part_ml + ((size_t)row * 8 + chunk) * 128;
#pragma unroll
    for (int r = 0; r < 4; ++r) {
      int q = w * 16 + (lane >> 4) * 4 + r;
#pragma unroll
      for (int dg = 0; dg < 4; ++dg) {
        int d = dg * 16 + (lane & 15);
        po[q * 64 + d] = o_acc[dg][r];
      }
      if ((lane & 15) == 0) {
        pml[q] = m_run[r];
        pml[64 + q] = l_run[r];
      }
    }
  }
}

// ---------------------------------------------------------------------------
// Kernel 4: merge 8 split-K partials per full row (48 rows).
// ---------------------------------------------------------------------------
__global__ __launch_bounds__(256) void combine_kernel(
    const float* __restrict__ part_o, const float* __restrict__ part_ml,
    float* __restrict__ out) {
  const int row = blockIdx.x;  // (b*12+h)*2 + (m==63)
  const int b = row / 24, h = (row >> 1) % 12, m = (row & 1) ? 63 : 0;
  const int t = threadIdx.x;
  const int q = t >> 2, d0 = (t & 3) * 16;

  float mc[8], lc[8];
  float M = -INFINITY;
#pragma unroll
  for (int c = 0; c < 8; ++c) {
    const float* pml = part_ml + ((size_t)row * 8 + c) * 128;
    mc[c] = pml[q];
    lc[c] = pml[64 + q];
    M = fmaxf(M, mc[c]);
  }
  float wgt[8], L = 0.f;
#pragma unroll
  for (int c = 0; c < 8; ++c) {
    wgt[c] = __expf(mc[c] - M);
    L += wgt[c] * lc[c];
  }
  f32x4 acc[4];
#pragma unroll
  for (int j = 0; j < 4; ++j) acc[j] = (f32x4){0.f, 0.f, 0.f, 0.f};
#pragma unroll
  for (int c = 0; c < 8; ++c) {
    const float* po = part_o + (((size_t)row * 8 + c) * 64 + q) * 64 + d0;
#pragma unroll
    for (int j = 0; j < 4; ++j) {
      f32x4 v = *(const f32x4*)(po + j * 4);
#pragma unroll
      for (int e = 0; e < 4; ++e) acc[j][e] += wgt[c] * v[e];
    }
  }
  const float inv = 1.0f / L;
  const int s = m * 64 + q;
  float* op = out + (((size_t)b * 4096 + s) * 12 + h) * 64 + d0;
#pragma unroll
  for (int j = 0; j < 4; ++j) {
    f32x4 v;
#pragma unroll
    for (int e = 0; e < 4; ++e) v[e] = acc[j][e] * inv;
    *(f32x4*)(op + j * 4) = v;
  }
}

// ---------------------------------------------------------------------------
extern "C" void kernel_launch(void* const* d_in, const int* in_sizes, int n_in,
                              void* d_out, int out_size, void* d_ws,
                              size_t ws_size, hipStream_t stream) {
  (void)in_sizes; (void)n_in; (void)out_size; (void)ws_size;
  const float* from_t = (const float*)d_in[0];
  const float* to_t = (const float*)d_in[1];
  const float* Wq = (const float*)d_in[2];
  const float* bq = (const float*)d_in[3];
  const float* Wk = (const float*)d_in[4];
  const float* bk = (const float*)d_in[5];
  const float* Wv = (const float*)d_in[6];
  const float* bv = (const float*)d_in[7];
  const int* to_mask = (const int*)d_in[8];
  const int* rand_attn = (const int*)d_in[9];
  float* out = (float*)d_out;

  unsigned short* Wt = (unsigned short*)d_ws;           // 3*768*768 bf16
  unsigned short* qkv = Wt + (size_t)3 * 768 * 768;     // 3*2*12*4096*64 bf16
  float* part_o = (float*)(qkv + (size_t)3 * 2 * 12 * 4096 * 64);  // 48*8*64*64 f32
  float* part_ml = part_o + (size_t)48 * 8 * 64 * 64;              // 48*8*2*64 f32

  wtrans_kernel<<<dim3(12, 12, 3), dim3(256), 0, stream>>>(Wq, Wk, Wv, Wt);
  qkv_gemm_kernel<<<dim3(64, 6, 3), dim3(256), 0, stream>>>(
      from_t, to_t, Wt, bq, bk, bv, qkv);
  attn_kernel<<<dim3(1488 + 384), dim3(256), 0, stream>>>(
      qkv, to_mask, rand_attn, out, part_o, part_ml);
  combine_kernel<<<dim3(48), dim3(256), 0, stream>>>(part_o, part_ml, out);
}